// Round 5
// baseline (2236.038 us; speedup 1.0000x reference)
//
#include <hip/hip_runtime.h>
#include <math.h>

// ---- Problem dimensions (fixed by setup_inputs) ----
#define B_   64
#define T_   41
#define E_   512
#define H_   512
#define V_   10000
#define NR   (B_*T_)     // 2624 rows of the (B,T) "matrixized" sequence
#define G4   (4*H_)      // 2048 gate width

// JAX PRNG mode: 1 = threefry_partitionable (modern JAX default),
//                0 = legacy/original threefry split + iota-halves bits.
// If this round fails with absmax ~O(1), flip to 0.
#define JAX_PARTITIONABLE 1

// ---------------- Threefry-2x32 (20 rounds, JAX-compatible) ----------------
__device__ __forceinline__ void tf2x32(unsigned k0, unsigned k1,
                                       unsigned x0, unsigned x1,
                                       unsigned& y0, unsigned& y1) {
  const unsigned ks2 = k0 ^ k1 ^ 0x1BD11BDAu;
#define TFR(r) { x0 += x1; x1 = (x1 << (r)) | (x1 >> (32 - (r))); x1 ^= x0; }
  x0 += k0; x1 += k1;
  TFR(13) TFR(15) TFR(26) TFR(6)
  x0 += k1;  x1 += ks2 + 1u;
  TFR(17) TFR(29) TFR(16) TFR(24)
  x0 += ks2; x1 += k0 + 2u;
  TFR(13) TFR(15) TFR(26) TFR(6)
  x0 += k0;  x1 += k1 + 3u;
  TFR(17) TFR(29) TFR(16) TFR(24)
  x0 += k1;  x1 += ks2 + 4u;
  TFR(13) TFR(15) TFR(26) TFR(6)
  x0 += ks2; x1 += k0 + 5u;
#undef TFR
  y0 = x0; y1 = x1;
}

// dk = jax.random.split(jax.random.key(42), 3); key data = (0, 42)
__device__ __forceinline__ void get_subkey(int i, unsigned& k0, unsigned& k1) {
#if JAX_PARTITIONABLE
  // fold-like split: key_i = threefry(key, (hi=0, lo=i)), both output words
  tf2x32(0u, 42u, 0u, (unsigned)i, k0, k1);
#else
  // original split: counts = iota(6) -> halves [0,1,2],[3,4,5]
  unsigned a0,a1,b0,b1,c0,c1;
  tf2x32(0u,42u,0u,3u,a0,a1);
  tf2x32(0u,42u,1u,4u,b0,b1);
  tf2x32(0u,42u,2u,5u,c0,c1);
  if (i==0) { k0=a0; k1=b0; } else if (i==1) { k0=c0; k1=a1; } else { k0=b1; k1=c1; }
#endif
}

// bernoulli(key, 0.5, shape)/0.5 : element `idx` of flat array of size n (n even)
__device__ __forceinline__ float mask_val(unsigned k0, unsigned k1,
                                          unsigned idx, unsigned n) {
  unsigned bits;
#if JAX_PARTITIONABLE
  unsigned y0, y1;
  tf2x32(k0, k1, 0u, idx, y0, y1);   // 64-bit counter = idx (hi=0, lo=idx)
  bits = y0 ^ y1;
#else
  const unsigned half = n >> 1;
  const unsigned lane = idx < half ? idx : idx - half;
  unsigned y0, y1;
  tf2x32(k0, k1, lane, lane + half, y0, y1);
  bits = (idx < half) ? y0 : y1;
#endif
  const float u = __uint_as_float((bits >> 9) | 0x3f800000u) - 1.0f;
  return (u < 0.5f) ? 2.0f : 0.0f;   // keep-prob 0.5, scale 1/0.5
}

// ---------------- mask generation ----------------
__global__ __launch_bounds__(256) void masks_kernel(float* __restrict__ wmask,
                                                    float* __restrict__ rmask) {
  const int i = blockIdx.x * 256 + threadIdx.x;   // 0..65535
  unsigned k0, k1;
  if (i < B_*E_) {
    get_subkey(0, k0, k1);
    wmask[i] = mask_val(k0, k1, (unsigned)i, B_*E_);
  } else {
    const int j = i - B_*E_;
    get_subkey(1, k0, k1);
    rmask[j] = mask_val(k0, k1, (unsigned)j, B_*H_);
  }
}

// rnn *= final_mask (dk[2]), in place
__global__ __launch_bounds__(256) void fmask_kernel(float* __restrict__ rnn, int n) {
  const int i = blockIdx.x * 256 + threadIdx.x;
  if (i >= n) return;
  unsigned k0, k1;
  get_subkey(2, k0, k1);
  rnn[i] *= mask_val(k0, k1, (unsigned)i, (unsigned)n);
}

// ---------------- x_seq build: [image_emb ; word_embs * word_mask] ----------------
__global__ __launch_bounds__(256) void xseq_kernel(const float* __restrict__ images_emb,
                                                   const int* __restrict__ targets,
                                                   const float* __restrict__ emb_table,
                                                   const float* __restrict__ wmask,
                                                   float* __restrict__ x_seq) {
  const int idx = blockIdx.x * 256 + threadIdx.x;
  if (idx >= NR * E_) return;
  const int k = idx & (E_ - 1);
  const int r = idx >> 9;       // E_=512
  const int t = r % T_;
  const int b = r / T_;
  float v;
  if (t == 0) {
    v = images_emb[(b << 9) + k];
  } else {
    const int tgt = targets[b * T_ + (t - 1)];
    v = emb_table[((size_t)tgt << 9) + k] * wmask[(b << 9) + k];
  }
  x_seq[idx] = v;
}

// ---------------- generic fp32 tiled GEMM: C = A(MxK) @ B(KxN) + bias ----------------
// BM=BN=64, BK=16, 256 threads, 4x4 per thread. M%64==0, K%16==0 assumed; N guarded.
__global__ __launch_bounds__(256) void gemm_bias(const float* __restrict__ A,
                                                 const float* __restrict__ Bm,
                                                 const float* __restrict__ bias,
                                                 float* __restrict__ C,
                                                 int M, int N, int K) {
  __shared__ float As[16][68];   // padded: conflict-free transposed stores
  __shared__ float Bs[16][64];
  const int tid = threadIdx.x;
  const int tn = tid & 15;
  const int tm = tid >> 4;
  const int m0 = blockIdx.y * 64;
  const int n0 = blockIdx.x * 64;
  float acc[4][4] = {};
  for (int k0 = 0; k0 < K; k0 += 16) {
    { // A tile 64x16, transposed into As[k][m]
      const int row = tid >> 2;
      const int kq  = (tid & 3) << 2;
      const float4 v = *(const float4*)(A + (size_t)(m0 + row) * K + k0 + kq);
      As[kq+0][row] = v.x; As[kq+1][row] = v.y; As[kq+2][row] = v.z; As[kq+3][row] = v.w;
    }
    { // B tile 16x64
      const int row = tid >> 4;
      const int cq  = (tid & 15) << 2;
      const int n   = n0 + cq;
      const float* bp = Bm + (size_t)(k0 + row) * N + n;
      float4 v;
      if (n + 3 < N) v = *(const float4*)bp;
      else {
        v.x = (n   < N) ? bp[0] : 0.f; v.y = (n+1 < N) ? bp[1] : 0.f;
        v.z = (n+2 < N) ? bp[2] : 0.f; v.w = (n+3 < N) ? bp[3] : 0.f;
      }
      *(float4*)&Bs[row][cq] = v;
    }
    __syncthreads();
#pragma unroll
    for (int kk = 0; kk < 16; ++kk) {
      const float4 av = *(const float4*)&As[kk][tm << 2];
      const float4 bv = *(const float4*)&Bs[kk][tn << 2];
      const float a[4] = {av.x, av.y, av.z, av.w};
      const float b[4] = {bv.x, bv.y, bv.z, bv.w};
#pragma unroll
      for (int i = 0; i < 4; ++i)
#pragma unroll
        for (int j = 0; j < 4; ++j) acc[i][j] += a[i] * b[j];
    }
    __syncthreads();
  }
  const int nc = n0 + (tn << 2);
  for (int i = 0; i < 4; ++i) {
    const int m = m0 + (tm << 2) + i;
    float* crow = C + (size_t)m * N + nc;
    if (n0 + 64 <= N) {
      float4 o;
      o.x = acc[i][0] + bias[nc];     o.y = acc[i][1] + bias[nc + 1];
      o.z = acc[i][2] + bias[nc + 2]; o.w = acc[i][3] + bias[nc + 3];
      *(float4*)crow = o;
    } else {
      for (int j = 0; j < 4; ++j)
        if (nc + j < N) crow[j] = acc[i][j] + bias[nc + j];
    }
  }
}

// ---------------- fused LSTM step: z = xz[:,t,:] + (h*rmask)@U ; gates ----------------
// grid (8 j-tiles of 64, 16 b-tiles of 4), 256 threads: wave bl = tid>>6 handles batch b0+bl
__global__ __launch_bounds__(256) void lstm_step(const float* __restrict__ xz,
                                                 const float* __restrict__ U,
                                                 const float* __restrict__ rmask,
                                                 float* __restrict__ h,
                                                 float* __restrict__ c,
                                                 float* __restrict__ rnn,
                                                 int t) {
  __shared__ float hm[H_ * 4];   // hm[k*4+bl] = h[b0+bl][k]*rmask[b0+bl][k]
  const int tid = threadIdx.x;
  const int b0 = blockIdx.y << 2;
  const int j0 = blockIdx.x << 6;
  for (int e = tid; e < 4 * H_; e += 256) {
    const int bl = e >> 9;
    const int k  = e & (H_ - 1);
    const int gi = ((b0 + bl) << 9) + k;
    hm[k * 4 + bl] = h[gi] * rmask[gi];
  }
  __syncthreads();
  const int bl = tid >> 6;
  const int nl = tid & 63;
  const int b  = b0 + bl;
  const int j  = j0 + nl;
  float a0 = 0.f, a1 = 0.f, a2 = 0.f, a3 = 0.f;
  const float* Up = U + j;
#pragma unroll 4
  for (int k = 0; k < H_; ++k) {
    const float hv = hm[k * 4 + bl];
    const float* u = Up + (size_t)k * G4;
    a0 += hv * u[0];
    a1 += hv * u[512];
    a2 += hv * u[1024];
    a3 += hv * u[1536];
  }
  const int r = b * T_ + t;
  const float* xzr = xz + (size_t)r * G4 + j;
  const float zi = a0 + xzr[0];
  const float zf = a1 + xzr[512];
  const float zg = a2 + xzr[1024];
  const float zo = a3 + xzr[1536];
  const float iv = 1.f / (1.f + expf(-zi));
  const float fv = 1.f / (1.f + expf(-zf));
  const float gv = tanhf(zg);
  const float ov = 1.f / (1.f + expf(-zo));
  const int hj = (b << 9) + j;
  const float cn = fv * c[hj] + iv * gv;
  const float hn = ov * tanhf(cn);
  c[hj] = cn;
  h[hj] = hn;
  rnn[(size_t)r * H_ + j] = hn;
}

// ---------------- launch ----------------
extern "C" void kernel_launch(void* const* d_in, const int* in_sizes, int n_in,
                              void* d_out, int out_size, void* d_ws, size_t ws_size,
                              hipStream_t stream) {
  // d_in[0] = pos_embs (UNUSED by reference)
  const float* images_emb = (const float*)d_in[1];
  const int*   targets    = (const int*)  d_in[2];
  const float* emb_table  = (const float*)d_in[3];
  const float* W          = (const float*)d_in[4];
  const float* U          = (const float*)d_in[5];
  const float* bvec       = (const float*)d_in[6];
  const float* Wo         = (const float*)d_in[7];
  const float* bo         = (const float*)d_in[8];
  float* out = (float*)d_out;

  // workspace layout (floats): total 8,192,000 (~32.8 MB)
  float* ws    = (float*)d_ws;
  float* x_seq = ws;                         // NR*E_   = 1,343,488
  float* xz    = x_seq + (size_t)NR * E_;    // NR*G4   = 5,373,952
  float* rnn   = xz    + (size_t)NR * G4;    // NR*H_   = 1,343,488
  float* h     = rnn   + (size_t)NR * H_;    // B_*H_   = 32,768
  float* c     = h     + B_ * H_;            // B_*H_   = 32,768
  float* wmask = c     + B_ * H_;            // B_*E_   = 32,768
  float* rmask = wmask + B_ * E_;            // B_*H_   = 32,768

  // 1) dropout masks (word + recurrent)
  masks_kernel<<<(B_*E_ + B_*H_) / 256, 256, 0, stream>>>(wmask, rmask);
  // 2) x_seq = [images_emb ; emb_table[targets]*word_mask]
  xseq_kernel<<<(NR * E_ + 255) / 256, 256, 0, stream>>>(images_emb, targets,
                                                         emb_table, wmask, x_seq);
  // 3) xz = x_seq @ W + b
  gemm_bias<<<dim3(G4 / 64, NR / 64), 256, 0, stream>>>(x_seq, W, bvec, xz, NR, G4, E_);
  // 4) h = c = 0
  hipMemsetAsync(h, 0, (size_t)2 * B_ * H_ * sizeof(float), stream);
  // 5) 41 recurrent steps
  for (int t = 0; t < T_; ++t)
    lstm_step<<<dim3(8, 16), 256, 0, stream>>>(xz, U, rmask, h, c, rnn, t);
  // 6) rnn *= final_mask
  fmask_kernel<<<(NR * H_ + 255) / 256, 256, 0, stream>>>(rnn, NR * H_);
  // 7) out = rnn @ Wo + bo
  gemm_bias<<<dim3((V_ + 63) / 64, NR / 64), 256, 0, stream>>>(rnn, Wo, bo, out,
                                                               NR, V_, E_);
}

// Round 6
// 1181.118 us; speedup vs baseline: 1.8932x; 1.8932x over previous
//
#include <hip/hip_runtime.h>
#include <math.h>

// ---- Problem dimensions (fixed by setup_inputs) ----
#define B_   64
#define T_   41
#define E_   512
#define H_   512
#define V_   10000
#define NR   (B_*T_)     // 2624 rows of the (B,T) "matrixized" sequence
#define G4   (4*H_)      // 2048 gate width

#define JAX_PARTITIONABLE 1   // confirmed correct in round 5 (absmax 3.9e-3)

// ---------------- Threefry-2x32 (20 rounds, JAX-compatible) ----------------
__device__ __forceinline__ void tf2x32(unsigned k0, unsigned k1,
                                       unsigned x0, unsigned x1,
                                       unsigned& y0, unsigned& y1) {
  const unsigned ks2 = k0 ^ k1 ^ 0x1BD11BDAu;
#define TFR(r) { x0 += x1; x1 = (x1 << (r)) | (x1 >> (32 - (r))); x1 ^= x0; }
  x0 += k0; x1 += k1;
  TFR(13) TFR(15) TFR(26) TFR(6)
  x0 += k1;  x1 += ks2 + 1u;
  TFR(17) TFR(29) TFR(16) TFR(24)
  x0 += ks2; x1 += k0 + 2u;
  TFR(13) TFR(15) TFR(26) TFR(6)
  x0 += k0;  x1 += k1 + 3u;
  TFR(17) TFR(29) TFR(16) TFR(24)
  x0 += k1;  x1 += ks2 + 4u;
  TFR(13) TFR(15) TFR(26) TFR(6)
  x0 += ks2; x1 += k0 + 5u;
#undef TFR
  y0 = x0; y1 = x1;
}

// dk = jax.random.split(jax.random.key(42), 3); key data = (0, 42)
__device__ __forceinline__ void get_subkey(int i, unsigned& k0, unsigned& k1) {
  tf2x32(0u, 42u, 0u, (unsigned)i, k0, k1);
}

// bernoulli(key, 0.5)/0.5 for flat element idx (partitionable random_bits)
__device__ __forceinline__ float mask_val(unsigned k0, unsigned k1, unsigned idx) {
  unsigned y0, y1;
  tf2x32(k0, k1, 0u, idx, y0, y1);
  const unsigned bits = y0 ^ y1;
  const float u = __uint_as_float((bits >> 9) | 0x3f800000u) - 1.0f;
  return (u < 0.5f) ? 2.0f : 0.0f;
}

// ---------------- mask generation ----------------
// wmask[b][e] (B*E) ; rmaskT[hj][b] (transposed recurrent mask)
__global__ __launch_bounds__(256) void masks_kernel(float* __restrict__ wmask,
                                                    float* __restrict__ rmaskT) {
  const int i = blockIdx.x * 256 + threadIdx.x;   // 0..65535
  unsigned k0, k1;
  if (i < B_*E_) {
    get_subkey(0, k0, k1);
    wmask[i] = mask_val(k0, k1, (unsigned)i);
  } else {
    const int j = i - B_*E_;          // flat index into (B,H) row-major
    get_subkey(1, k0, k1);
    const float v = mask_val(k0, k1, (unsigned)j);
    const int b  = j >> 9;
    const int hj = j & (H_ - 1);
    rmaskT[(hj << 6) + b] = v;
  }
}

// ---------------- x_seq build: [image_emb ; word_embs * word_mask] ----------------
__global__ __launch_bounds__(256) void xseq_kernel(const float* __restrict__ images_emb,
                                                   const int* __restrict__ targets,
                                                   const float* __restrict__ emb_table,
                                                   const float* __restrict__ wmask,
                                                   float* __restrict__ x_seq) {
  const int idx = blockIdx.x * 256 + threadIdx.x;
  if (idx >= NR * E_) return;
  const int k = idx & (E_ - 1);
  const int r = idx >> 9;       // E_=512
  const int t = r % T_;
  const int b = r / T_;
  float v;
  if (t == 0) {
    v = images_emb[(b << 9) + k];
  } else {
    const int tgt = targets[b * T_ + (t - 1)];
    v = emb_table[((size_t)tgt << 9) + k] * wmask[(b << 9) + k];
  }
  x_seq[idx] = v;
}

// ---------------- generic fp32 tiled GEMM: C = A(MxK) @ B(KxN) + bias ----------------
// BM=BN=64, BK=16, 256 threads, 4x4 per thread. M%64==0, K%16==0 assumed; N guarded.
__global__ __launch_bounds__(256) void gemm_bias(const float* __restrict__ A,
                                                 const float* __restrict__ Bm,
                                                 const float* __restrict__ bias,
                                                 float* __restrict__ C,
                                                 int M, int N, int K) {
  __shared__ float As[16][68];
  __shared__ float Bs[16][64];
  const int tid = threadIdx.x;
  const int tn = tid & 15;
  const int tm = tid >> 4;
  const int m0 = blockIdx.y * 64;
  const int n0 = blockIdx.x * 64;
  float acc[4][4] = {};
  for (int k0 = 0; k0 < K; k0 += 16) {
    {
      const int row = tid >> 2;
      const int kq  = (tid & 3) << 2;
      const float4 v = *(const float4*)(A + (size_t)(m0 + row) * K + k0 + kq);
      As[kq+0][row] = v.x; As[kq+1][row] = v.y; As[kq+2][row] = v.z; As[kq+3][row] = v.w;
    }
    {
      const int row = tid >> 4;
      const int cq  = (tid & 15) << 2;
      const int n   = n0 + cq;
      const float* bp = Bm + (size_t)(k0 + row) * N + n;
      float4 v;
      if (n + 3 < N) v = *(const float4*)bp;
      else {
        v.x = (n   < N) ? bp[0] : 0.f; v.y = (n+1 < N) ? bp[1] : 0.f;
        v.z = (n+2 < N) ? bp[2] : 0.f; v.w = (n+3 < N) ? bp[3] : 0.f;
      }
      *(float4*)&Bs[row][cq] = v;
    }
    __syncthreads();
#pragma unroll
    for (int kk = 0; kk < 16; ++kk) {
      const float4 av = *(const float4*)&As[kk][tm << 2];
      const float4 bv = *(const float4*)&Bs[kk][tn << 2];
      const float a[4] = {av.x, av.y, av.z, av.w};
      const float b[4] = {bv.x, bv.y, bv.z, bv.w};
#pragma unroll
      for (int i = 0; i < 4; ++i)
#pragma unroll
        for (int j = 0; j < 4; ++j) acc[i][j] += a[i] * b[j];
    }
    __syncthreads();
  }
  const int nc = n0 + (tn << 2);
  for (int i = 0; i < 4; ++i) {
    const int m = m0 + (tm << 2) + i;
    float* crow = C + (size_t)m * N + nc;
    if (n0 + 64 <= N) {
      float4 o;
      o.x = acc[i][0] + bias[nc];     o.y = acc[i][1] + bias[nc + 1];
      o.z = acc[i][2] + bias[nc + 2]; o.w = acc[i][3] + bias[nc + 3];
      *(float4*)crow = o;
    } else {
      for (int j = 0; j < 4; ++j)
        if (nc + j < N) crow[j] = acc[i][j] + bias[nc + j];
    }
  }
}

// ---------------- LSTM step, v2 ----------------
// Grid: dim3(32, 8) = 256 blocks (1/CU), 512 threads (8 waves, 2/SIMD).
// Block tile: 16 h-cols (blockIdx.x) x 8 batches (blockIdx.y); K=512 split
// across 4 k-quarters (kq = tid>>7), LDS reduction, epilogue on tid<128.
// hmT[k][b] = h[b][k]*rmask[b][k] is double-buffered across steps (race-free:
// step t reads hmT_cur written entirely by step t-1's epilogue).
// fmask (dk[2]) is fused into the rnn write.
__global__ __launch_bounds__(512) void lstm_step2(const float* __restrict__ xz,
                                                  const float* __restrict__ U,
                                                  const float* __restrict__ rmaskT,
                                                  const float* __restrict__ hmT_cur,
                                                  float* __restrict__ hmT_next,
                                                  float* __restrict__ c,
                                                  float* __restrict__ rnn,
                                                  int t) {
  __shared__ float part[4][4][128];   // [gate][kq][o]
  const int tid = threadIdx.x;
  const int kq  = tid >> 7;           // 0..3
  const int o   = tid & 127;          // 0..127
  const int bo  = o >> 4;             // 0..7
  const int jo  = o & 15;             // 0..15
  const int b   = (blockIdx.y << 3) + bo;
  const int hj  = (blockIdx.x << 4) + jo;

  float a0 = 0.f, a1 = 0.f, a2 = 0.f, a3 = 0.f;
  const float* Up = U + hj;
  const int k0 = kq << 7;
#pragma unroll 4
  for (int k = k0; k < k0 + 128; ++k) {
    const float hv = hmT_cur[(k << 6) + b];     // 16B-contig per wave: 1 line
    const float* u = Up + ((size_t)k << 11);    // k*2048
    a0 += hv * u[0];
    a1 += hv * u[512];
    a2 += hv * u[1024];
    a3 += hv * u[1536];
  }
  part[0][kq][o] = a0; part[1][kq][o] = a1;
  part[2][kq][o] = a2; part[3][kq][o] = a3;
  __syncthreads();

  if (tid < 128) {
    const int r = b * T_ + t;
    const float* xzr = xz + (size_t)r * G4 + hj;
    float z[4];
#pragma unroll
    for (int g = 0; g < 4; ++g)
      z[g] = xzr[(size_t)g << 9] + part[g][0][tid] + part[g][1][tid]
           + part[g][2][tid] + part[g][3][tid];
    const float iv = 1.f / (1.f + expf(-z[0]));
    const float fv = 1.f / (1.f + expf(-z[1]));
    const float gv = tanhf(z[2]);
    const float ov = 1.f / (1.f + expf(-z[3]));
    const int ci = (b << 9) + hj;
    const float cn = fv * c[ci] + iv * gv;
    c[ci] = cn;
    const float hn = ov * tanhf(cn);
    const int ti = (hj << 6) + b;
    hmT_next[ti] = hn * rmaskT[ti];             // recurrent-masked, transposed
    unsigned fk0, fk1;
    get_subkey(2, fk0, fk1);                    // constant-folded
    const unsigned fidx = (unsigned)(r * H_ + hj);
    rnn[(size_t)r * H_ + hj] = hn * mask_val(fk0, fk1, fidx);  // final mask fused
  }
}

// ---------------- launch ----------------
extern "C" void kernel_launch(void* const* d_in, const int* in_sizes, int n_in,
                              void* d_out, int out_size, void* d_ws, size_t ws_size,
                              hipStream_t stream) {
  // d_in[0] = pos_embs (UNUSED by reference)
  const float* images_emb = (const float*)d_in[1];
  const int*   targets    = (const int*)  d_in[2];
  const float* emb_table  = (const float*)d_in[3];
  const float* W          = (const float*)d_in[4];
  const float* U          = (const float*)d_in[5];
  const float* bvec       = (const float*)d_in[6];
  const float* Wo         = (const float*)d_in[7];
  const float* bo         = (const float*)d_in[8];
  float* out = (float*)d_out;

  // workspace layout (floats)
  float* ws     = (float*)d_ws;
  float* x_seq  = ws;                          // NR*E   = 1,343,488
  float* xz     = x_seq  + (size_t)NR * E_;    // NR*G4  = 5,373,952
  float* rnn    = xz     + (size_t)NR * G4;    // NR*H   = 1,343,488
  float* hmA    = rnn    + (size_t)NR * H_;    // B*H    = 32,768
  float* c      = hmA    + B_ * H_;            // B*H    = 32,768  (adjacent to hmA)
  float* hmB    = c      + B_ * H_;            // B*H    = 32,768
  float* wmask  = hmB    + B_ * H_;            // B*E    = 32,768
  float* rmaskT = wmask  + B_ * E_;            // B*H    = 32,768

  // 1) dropout masks (word + transposed recurrent)
  masks_kernel<<<(B_*E_ + B_*H_) / 256, 256, 0, stream>>>(wmask, rmaskT);
  // 2) x_seq = [images_emb ; emb_table[targets]*word_mask]
  xseq_kernel<<<(NR * E_ + 255) / 256, 256, 0, stream>>>(images_emb, targets,
                                                         emb_table, wmask, x_seq);
  // 3) xz = x_seq @ W + b
  gemm_bias<<<dim3(G4 / 64, NR / 64), 256, 0, stream>>>(x_seq, W, bvec, xz, NR, G4, E_);
  // 4) hmT(buf A) = 0, c = 0   (hmA and c are adjacent -> one memset)
  hipMemsetAsync(hmA, 0, (size_t)2 * B_ * H_ * sizeof(float), stream);
  // 5) 41 recurrent steps, double-buffered hmT
  for (int t = 0; t < T_; ++t) {
    const float* cur = (t & 1) ? hmB : hmA;
    float*       nxt = (t & 1) ? hmA : hmB;
    lstm_step2<<<dim3(H_ / 16, B_ / 8), 512, 0, stream>>>(xz, U, rmaskT, cur, nxt,
                                                          c, rnn, t);
  }
  // 6) out = rnn @ Wo + bo   (rnn already final-masked)
  gemm_bias<<<dim3((V_ + 63) / 64, NR / 64), 256, 0, stream>>>(rnn, Wo, bo, out,
                                                               NR, V_, E_);
}

// Round 11
// 931.944 us; speedup vs baseline: 2.3993x; 1.2674x over previous
//
#include <hip/hip_runtime.h>
#include <hip/hip_bf16.h>
#include <math.h>

// ---- Problem dimensions (fixed by setup_inputs) ----
#define B_   64
#define T_   41
#define E_   512
#define H_   512
#define V_   10000
#define NR   (B_*T_)     // 2624
#define G4   (4*H_)      // 2048

typedef __attribute__((ext_vector_type(8))) short bf16x8;   // 8 bf16 = 4 VGPR
typedef __attribute__((ext_vector_type(4))) float f32x4;

// ---------------- Threefry-2x32 (JAX partitionable — CONFIRMED r5) ----------
__device__ __forceinline__ void tf2x32(unsigned k0, unsigned k1,
                                       unsigned x0, unsigned x1,
                                       unsigned& y0, unsigned& y1) {
  const unsigned ks2 = k0 ^ k1 ^ 0x1BD11BDAu;
#define TFR(r) { x0 += x1; x1 = (x1 << (r)) | (x1 >> (32 - (r))); x1 ^= x0; }
  x0 += k0; x1 += k1;
  TFR(13) TFR(15) TFR(26) TFR(6)
  x0 += k1;  x1 += ks2 + 1u;
  TFR(17) TFR(29) TFR(16) TFR(24)
  x0 += ks2; x1 += k0 + 2u;
  TFR(13) TFR(15) TFR(26) TFR(6)
  x0 += k0;  x1 += k1 + 3u;
  TFR(17) TFR(29) TFR(16) TFR(24)
  x0 += k1;  x1 += ks2 + 4u;
  TFR(13) TFR(15) TFR(26) TFR(6)
  x0 += ks2; x1 += k0 + 5u;
#undef TFR
  y0 = x0; y1 = x1;
}

__device__ __forceinline__ void get_subkey(int i, unsigned& k0, unsigned& k1) {
  tf2x32(0u, 42u, 0u, (unsigned)i, k0, k1);
}

__device__ __forceinline__ float mask_val(unsigned k0, unsigned k1, unsigned idx) {
  unsigned y0, y1;
  tf2x32(k0, k1, 0u, idx, y0, y1);
  const unsigned bits = y0 ^ y1;
  const float u = __uint_as_float((bits >> 9) | 0x3f800000u) - 1.0f;
  return (u < 0.5f) ? 2.0f : 0.0f;
}

// ---------------- mask generation ----------------
__global__ __launch_bounds__(256) void masks_kernel(float* __restrict__ wmask,
                                                    float* __restrict__ rmaskT) {
  const int i = blockIdx.x * 256 + threadIdx.x;
  unsigned k0, k1;
  if (i < B_*E_) {
    get_subkey(0, k0, k1);
    wmask[i] = mask_val(k0, k1, (unsigned)i);
  } else {
    const int j = i - B_*E_;
    get_subkey(1, k0, k1);
    const float v = mask_val(k0, k1, (unsigned)j);
    const int b  = j >> 9;
    const int hj = j & (H_ - 1);
    rmaskT[(hj << 6) + b] = v;
  }
}

// ---------------- x_seq build ----------------
__global__ __launch_bounds__(256) void xseq_kernel(const float* __restrict__ images_emb,
                                                   const int* __restrict__ targets,
                                                   const float* __restrict__ emb_table,
                                                   const float* __restrict__ wmask,
                                                   float* __restrict__ x_seq) {
  const int idx = blockIdx.x * 256 + threadIdx.x;
  if (idx >= NR * E_) return;
  const int k = idx & (E_ - 1);
  const int r = idx >> 9;
  const int t = r % T_;
  const int b = r / T_;
  float v;
  if (t == 0) {
    v = images_emb[(b << 9) + k];
  } else {
    const int tgt = targets[b * T_ + (t - 1)];
    v = emb_table[((size_t)tgt << 9) + k] * wmask[(b << 9) + k];
  }
  x_seq[idx] = v;
}

// ---------------- fp32 tiled GEMM (xz GEMM + fallback path) ----------------
__global__ __launch_bounds__(256) void gemm_bias(const float* __restrict__ A,
                                                 const float* __restrict__ Bm,
                                                 const float* __restrict__ bias,
                                                 float* __restrict__ C,
                                                 int M, int N, int K) {
  __shared__ float As[16][68];
  __shared__ float Bs[16][64];
  const int tid = threadIdx.x;
  const int tn = tid & 15;
  const int tm = tid >> 4;
  const int m0 = blockIdx.y * 64;
  const int n0 = blockIdx.x * 64;
  float acc[4][4] = {};
  for (int k0 = 0; k0 < K; k0 += 16) {
    {
      const int row = tid >> 2;
      const int kq  = (tid & 3) << 2;
      const float4 v = *(const float4*)(A + (size_t)(m0 + row) * K + k0 + kq);
      As[kq+0][row] = v.x; As[kq+1][row] = v.y; As[kq+2][row] = v.z; As[kq+3][row] = v.w;
    }
    {
      const int row = tid >> 4;
      const int cq  = (tid & 15) << 2;
      const int n   = n0 + cq;
      const float* bp = Bm + (size_t)(k0 + row) * N + n;
      float4 v;
      if (n + 3 < N) v = *(const float4*)bp;
      else {
        v.x = (n   < N) ? bp[0] : 0.f; v.y = (n+1 < N) ? bp[1] : 0.f;
        v.z = (n+2 < N) ? bp[2] : 0.f; v.w = (n+3 < N) ? bp[3] : 0.f;
      }
      *(float4*)&Bs[row][cq] = v;
    }
    __syncthreads();
#pragma unroll
    for (int kk = 0; kk < 16; ++kk) {
      const float4 av = *(const float4*)&As[kk][tm << 2];
      const float4 bv = *(const float4*)&Bs[kk][tn << 2];
      const float a[4] = {av.x, av.y, av.z, av.w};
      const float b[4] = {bv.x, bv.y, bv.z, bv.w};
#pragma unroll
      for (int i = 0; i < 4; ++i)
#pragma unroll
        for (int j = 0; j < 4; ++j) acc[i][j] += a[i] * b[j];
    }
    __syncthreads();
  }
  const int nc = n0 + (tn << 2);
  for (int i = 0; i < 4; ++i) {
    const int m = m0 + (tm << 2) + i;
    float* crow = C + (size_t)m * N + nc;
    if (n0 + 64 <= N) {
      float4 o;
      o.x = acc[i][0] + bias[nc];     o.y = acc[i][1] + bias[nc + 1];
      o.z = acc[i][2] + bias[nc + 2]; o.w = acc[i][3] + bias[nc + 3];
      *(float4*)crow = o;
    } else {
      for (int j = 0; j < 4; ++j)
        if (nc + j < N) crow[j] = acc[i][j] + bias[nc + j];
    }
  }
}

// ---------------- LSTM step, v3 ----------------
__global__ __launch_bounds__(512) void lstm_step3(const float* __restrict__ xz,
                                                  const float* __restrict__ U,
                                                  const float* __restrict__ rmaskT,
                                                  const float* __restrict__ hmT_cur,
                                                  float* __restrict__ hmT_next,
                                                  float* __restrict__ c,
                                                  float* __restrict__ rnn,
                                                  int t) {
  __shared__ float4 part[8][64];
  const int tid = threadIdx.x;
  const int kq  = tid >> 6;
  const int o   = tid & 63;
  const int bo  = o >> 4;
  const int sub = o & 15;
  const int g   = sub >> 2;
  const int jq  = sub & 3;
  const int b     = (blockIdx.y << 2) + bo;
  const int jbase = (blockIdx.x << 4) + (jq << 2);
  const int col   = (g << 9) + jbase;

  float4 acc = {0.f, 0.f, 0.f, 0.f};
  const float* Ucol = U + col;
  const int k0 = kq << 6;
#pragma unroll 4
  for (int k = k0; k < k0 + 64; ++k) {
    const float  hv = hmT_cur[(k << 6) + b];
    const float4 uv = *(const float4*)(Ucol + ((size_t)k << 11));
    acc.x += hv * uv.x;
    acc.y += hv * uv.y;
    acc.z += hv * uv.z;
    acc.w += hv * uv.w;
  }
  part[kq][o] = acc;
  __syncthreads();

  if (tid < 64) {
    const int bo_e = tid >> 4;
    const int je   = tid & 15;
    const int b_e  = (blockIdx.y << 2) + bo_e;
    const int j_e  = (blockIdx.x << 4) + je;
    const int jq_e = je >> 2;
    const int jj   = je & 3;
    const int r    = b_e * T_ + t;
    const float* xzr = xz + (size_t)r * G4 + j_e;
    float z[4];
#pragma unroll
    for (int gg = 0; gg < 4; ++gg) {
      const int oo = (bo_e << 4) + (gg << 2) + jq_e;
      float s = 0.f;
#pragma unroll
      for (int kk = 0; kk < 8; ++kk) {
        const float4 p = part[kk][oo];
        s += (jj == 0) ? p.x : (jj == 1) ? p.y : (jj == 2) ? p.z : p.w;
      }
      z[gg] = s + xzr[(size_t)gg << 9];
    }
    const float iv = 1.f / (1.f + expf(-z[0]));
    const float fv = 1.f / (1.f + expf(-z[1]));
    const float gv = tanhf(z[2]);
    const float ov = 1.f / (1.f + expf(-z[3]));
    const int ci = (b_e << 9) + j_e;
    const float cn = fv * c[ci] + iv * gv;
    c[ci] = cn;
    const float hn = ov * tanhf(cn);
    const int ti = (j_e << 6) + b_e;
    hmT_next[ti] = hn * rmaskT[ti];
    unsigned fk0, fk1;
    get_subkey(2, fk0, fk1);
    const unsigned fidx = (unsigned)(r * H_ + j_e);
    rnn[(size_t)r * H_ + j_e] = hn * mask_val(fk0, fk1, fidx);
  }
}

// ---------------- Wo -> bf16 transposed WoT[n][k] (LDS tile transpose) -------
__global__ __launch_bounds__(256) void convert_wot(const float* __restrict__ Wo,
                                                   __hip_bfloat16* __restrict__ WoT) {
  __shared__ float tile[64][65];
  const int tid = threadIdx.x;
  const int n0 = blockIdx.x << 6;
  const int k0 = blockIdx.y << 6;
#pragma unroll
  for (int i = 0; i < 4; ++i) {
    const int lr = (tid >> 4) + (i << 4);          // k-row 0..63
    const int lc = (tid & 15) << 2;                // n-col 0..60
    const int k  = k0 + lr;
    const int n  = n0 + lc;
    float4 v = {0.f, 0.f, 0.f, 0.f};
    const float* p = Wo + (size_t)k * V_ + n;
    if (n + 3 < V_) v = *(const float4*)p;
    else if (n < V_) {
      v.x = p[0];
      if (n + 1 < V_) v.y = p[1];
      if (n + 2 < V_) v.z = p[2];
    }
    tile[lr][lc] = v.x; tile[lr][lc+1] = v.y; tile[lr][lc+2] = v.z; tile[lr][lc+3] = v.w;
  }
  __syncthreads();
  const int wn = tid >> 2;                         // n-row 0..63
  const int wk = (tid & 3) << 4;                   // k chunk of 16
  if (n0 + wn < V_) {
    alignas(16) __hip_bfloat16 buf[16];
#pragma unroll
    for (int i = 0; i < 16; ++i) buf[i] = __float2bfloat16(tile[wk + i][wn]);
    __hip_bfloat16* dst = WoT + (size_t)(n0 + wn) * H_ + k0 + wk;
    *(uint4*)dst       = *(uint4*)&buf[0];
    *(uint4*)(dst + 8) = *(uint4*)&buf[8];
  }
}

// ---------------- rnn fp32 -> bf16 ----------------
__global__ __launch_bounds__(256) void convert_rnn(const float* __restrict__ rnn,
                                                   __hip_bfloat16* __restrict__ rnn_bf) {
  const int i = (blockIdx.x * 256 + threadIdx.x) << 3;
  if (i >= NR * H_) return;
  const float4 v0 = *(const float4*)(rnn + i);
  const float4 v1 = *(const float4*)(rnn + i + 4);
  alignas(16) __hip_bfloat16 b[8];
  b[0] = __float2bfloat16(v0.x); b[1] = __float2bfloat16(v0.y);
  b[2] = __float2bfloat16(v0.z); b[3] = __float2bfloat16(v0.w);
  b[4] = __float2bfloat16(v1.x); b[5] = __float2bfloat16(v1.y);
  b[6] = __float2bfloat16(v1.z); b[7] = __float2bfloat16(v1.w);
  *(uint4*)(rnn_bf + i) = *(uint4*)b;
}

// ---------------- bf16 MFMA output GEMM: out = rnn_bf @ WoT^T + bo ----------
// BM=64, BN=128 (N-guarded), BK=32, 256 threads = 4 waves.
// Wave (wr,wc): rows wr*32..+32, cols wc*64..+64 -> acc[2][4] 16x16 fragments.
__global__ __launch_bounds__(256) void gemm_out_mfma(const __hip_bfloat16* __restrict__ A,
                                                     const __hip_bfloat16* __restrict__ BT,
                                                     const float* __restrict__ bias,
                                                     float* __restrict__ C) {
  __shared__ short As[64][40];
  __shared__ short Bs[128][40];
  const int tid  = threadIdx.x;
  const int m0   = blockIdx.y << 6;
  const int n0   = blockIdx.x << 7;
  const int lane = tid & 63;
  const int wv   = tid >> 6;
  const int wr   = wv >> 1;
  const int wc   = wv & 1;
  const int l15  = lane & 15;
  const int l4   = lane >> 4;

  f32x4 acc[2][4];
#pragma unroll
  for (int m = 0; m < 2; ++m)
#pragma unroll
    for (int n = 0; n < 4; ++n) acc[m][n] = (f32x4){0.f, 0.f, 0.f, 0.f};

  const int srow = tid >> 2;          // 0..63
  const int ko8  = (tid & 3) << 3;    // 0,8,16,24

  for (int k0 = 0; k0 < H_; k0 += 32) {
    *(uint4*)&As[srow][ko8] =
        *(const uint4*)(A + (size_t)(m0 + srow) * H_ + k0 + ko8);
#pragma unroll
    for (int it = 0; it < 2; ++it) {
      const int brow = srow + (it << 6);
      uint4 v = {0u, 0u, 0u, 0u};
      if (n0 + brow < V_)
        v = *(const uint4*)(BT + (size_t)(n0 + brow) * H_ + k0 + ko8);
      *(uint4*)&Bs[brow][ko8] = v;
    }
    __syncthreads();
    bf16x8 af[2], bfr[4];
#pragma unroll
    for (int m = 0; m < 2; ++m)
      af[m] = *(const bf16x8*)&As[(wr << 5) + (m << 4) + l15][l4 << 3];
#pragma unroll
    for (int n = 0; n < 4; ++n)
      bfr[n] = *(const bf16x8*)&Bs[(wc << 6) + (n << 4) + l15][l4 << 3];
#pragma unroll
    for (int m = 0; m < 2; ++m)
#pragma unroll
      for (int n = 0; n < 4; ++n)
        acc[m][n] = __builtin_amdgcn_mfma_f32_16x16x32_bf16(af[m], bfr[n],
                                                            acc[m][n], 0, 0, 0);
    __syncthreads();
  }
  // epilogue: C/D layout col=lane&15, row=(lane>>4)*4+q  [m89-verified]
#pragma unroll
  for (int m = 0; m < 2; ++m) {
    const int row = m0 + (wr << 5) + (m << 4) + (l4 << 2);
#pragma unroll
    for (int n = 0; n < 4; ++n) {
      const int col = n0 + (wc << 6) + (n << 4) + l15;
      if (col < V_) {
        const float bb = bias[col];
#pragma unroll
        for (int q = 0; q < 4; ++q)
          C[(size_t)(row + q) * V_ + col] = acc[m][n][q] + bb;
      }
    }
  }
}

// ---------------- launch ----------------
extern "C" void kernel_launch(void* const* d_in, const int* in_sizes, int n_in,
                              void* d_out, int out_size, void* d_ws, size_t ws_size,
                              hipStream_t stream) {
  const float* images_emb = (const float*)d_in[1];
  const int*   targets    = (const int*)  d_in[2];
  const float* emb_table  = (const float*)d_in[3];
  const float* W          = (const float*)d_in[4];
  const float* U          = (const float*)d_in[5];
  const float* bvec       = (const float*)d_in[6];
  const float* Wo         = (const float*)d_in[7];
  const float* bo         = (const float*)d_in[8];
  float* out = (float*)d_out;

  // workspace layout (float slots)
  float* ws     = (float*)d_ws;
  float* x_seq  = ws;                          // 1,343,488
  float* xz     = x_seq  + (size_t)NR * E_;    // 5,373,952
  float* rnn    = xz     + (size_t)NR * G4;    // 1,343,488
  float* hmA    = rnn    + (size_t)NR * H_;    //    32,768
  float* c      = hmA    + B_ * H_;            //    32,768 (adjacent to hmA)
  float* hmB    = c      + B_ * H_;            //    32,768
  float* wmask  = hmB    + B_ * H_;            //    32,768
  float* rmaskT = wmask  + B_ * E_;            //    32,768
  float* extra  = rmaskT + B_ * H_;
  __hip_bfloat16* rnn_bf = (__hip_bfloat16*)extra;                  // 2.69 MB
  __hip_bfloat16* WoT    = (__hip_bfloat16*)(extra + 671744);       // 10.24 MB
  const size_t need_bytes = (size_t)(671744 + 2560000) * 4 +
                            ((size_t)(rmaskT + B_ * H_ - ws)) * 4;  // = 45.8 MB
  const bool use_mfma = ws_size >= need_bytes;

  // 1) dropout masks
  masks_kernel<<<(B_*E_ + B_*H_) / 256, 256, 0, stream>>>(wmask, rmaskT);
  // 2) x_seq
  xseq_kernel<<<(NR * E_ + 255) / 256, 256, 0, stream>>>(images_emb, targets,
                                                         emb_table, wmask, x_seq);
  // 3) xz = x_seq @ W + b
  gemm_bias<<<dim3(G4 / 64, NR / 64), 256, 0, stream>>>(x_seq, W, bvec, xz, NR, G4, E_);
  // 4) hmA = c = 0
  hipMemsetAsync(hmA, 0, (size_t)2 * B_ * H_ * sizeof(float), stream);
  // 4b) Wo -> bf16 transposed (MFMA path only)
  if (use_mfma)
    convert_wot<<<dim3((V_ + 63) / 64, H_ / 64), 256, 0, stream>>>(Wo, WoT);
  // 5) 41 recurrent steps, double-buffered hmT
  for (int t = 0; t < T_; ++t) {
    const float* cur = (t & 1) ? hmB : hmA;
    float*       nxt = (t & 1) ? hmA : hmB;
    lstm_step3<<<dim3(H_ / 16, B_ / 4), 512, 0, stream>>>(xz, U, rmaskT, cur, nxt,
                                                          c, rnn, t);
  }
  // 6) out = rnn @ Wo + bo
  if (use_mfma) {
    convert_rnn<<<(NR * H_ / 8 + 255) / 256, 256, 0, stream>>>(rnn, rnn_bf);
    gemm_out_mfma<<<dim3((V_ + 127) / 128, NR / 64), 256, 0, stream>>>(rnn_bf, WoT,
                                                                       bo, out);
  } else {
    gemm_bias<<<dim3((V_ + 63) / 64, NR / 64), 256, 0, stream>>>(rnn, Wo, bo, out,
                                                                 NR, V_, E_);
  }
}